// Round 1
// baseline (508.235 us; speedup 1.0000x reference)
//
#include <hip/hip_runtime.h>
#include <cstdint>

#define NB 4096
#define NT 512
#define NF 64
#define NH 3
#define NG 12   // 4*H

__device__ __forceinline__ float fsig(float x) {
    return 1.0f / (1.0f + __expf(-x));
}
__device__ __forceinline__ float ftanh(float x) {
    // tanh(x) = 1 - 2/(1+e^{2x}); handles +-inf gracefully
    return 1.0f - 2.0f / (1.0f + __expf(2.0f * x));
}

// K1: pre[(b*CT + tl)*12 + g] = bias[g] + sum_f x[b, t0+tl, f] * W[f,g]
// One thread per row (b, tl). Consecutive threads = consecutive tl within one b
// (CT >= 64), so a wave streams 16 KB of contiguous x. W broadcast from LDS.
__global__ __launch_bounds__(256) void k1_proj(
        const float* __restrict__ x, const float* __restrict__ W,
        const float* __restrict__ bias, float* __restrict__ pre,
        int t0, int CT, int ctShift) {
    __shared__ float Wl[NF * NG];
    int tid = threadIdx.x;
    for (int i = tid; i < NF * NG; i += 256) Wl[i] = W[i];
    __syncthreads();

    int r = blockIdx.x * 256 + tid;          // row index within chunk
    int b = r >> ctShift;
    int tl = r & (CT - 1);
    const float4* xrow = (const float4*)(x + ((size_t)b * NT + (size_t)(t0 + tl)) * NF);

    float acc[NG];
    #pragma unroll
    for (int g = 0; g < NG; ++g) acc[g] = bias[g];

    #pragma unroll
    for (int f4 = 0; f4 < NF / 4; ++f4) {
        float4 xv = xrow[f4];
        #pragma unroll
        for (int ff = 0; ff < 4; ++ff) {
            float xf = (ff == 0) ? xv.x : (ff == 1) ? xv.y : (ff == 2) ? xv.z : xv.w;
            const float4* wr = (const float4*)&Wl[(f4 * 4 + ff) * NG];
            float4 w0 = wr[0];
            float4 w1 = wr[1];
            float4 w2 = wr[2];
            acc[0] += xf * w0.x; acc[1] += xf * w0.y; acc[2]  += xf * w0.z; acc[3]  += xf * w0.w;
            acc[4] += xf * w1.x; acc[5] += xf * w1.y; acc[6]  += xf * w1.z; acc[7]  += xf * w1.w;
            acc[8] += xf * w2.x; acc[9] += xf * w2.y; acc[10] += xf * w2.z; acc[11] += xf * w2.w;
        }
    }

    float4* po = (float4*)(pre + (size_t)r * NG);
    po[0] = make_float4(acc[0], acc[1], acc[2],  acc[3]);
    po[1] = make_float4(acc[4], acc[5], acc[6],  acc[7]);
    po[2] = make_float4(acc[8], acc[9], acc[10], acc[11]);
}

// K2: sequential LSTM scan over CT steps; one lane per batch element.
// pre laid out [b][tl][12] so each lane streams its own contiguous 48B/step.
__global__ __launch_bounds__(64) void k2_scan(
        const float* __restrict__ pre, const float* __restrict__ U,
        const float* __restrict__ Wd, const float* __restrict__ bd,
        float* __restrict__ state, float* __restrict__ out,
        int t0, int CT, int last) {
    int b = blockIdx.x * 64 + threadIdx.x;

    float u[NH][NG];
    #pragma unroll
    for (int j = 0; j < NH; ++j)
        #pragma unroll
        for (int g = 0; g < NG; ++g) u[j][g] = U[j * NG + g];

    float* hs = state;               // [NB*3]
    float* cs = state + NB * NH;     // [NB*3]
    float h0, h1, h2, c0, c1, c2;
    if (t0 == 0) {
        h0 = h1 = h2 = c0 = c1 = c2 = 0.0f;
    } else {
        h0 = hs[b * 3 + 0]; h1 = hs[b * 3 + 1]; h2 = hs[b * 3 + 2];
        c0 = cs[b * 3 + 0]; c1 = cs[b * 3 + 1]; c2 = cs[b * 3 + 2];
    }

    const float4* p = (const float4*)(pre + (size_t)b * CT * NG);
    float4 pa = p[0], pb = p[1], pc = p[2];

    for (int tl = 0; tl < CT; ++tl) {
        float4 na, nb_, nc;
        if (tl + 1 < CT) {
            na  = p[(tl + 1) * 3 + 0];
            nb_ = p[(tl + 1) * 3 + 1];
            nc  = p[(tl + 1) * 3 + 2];
        } else {
            na = pa; nb_ = pb; nc = pc;
        }

        float z[NG] = {pa.x, pa.y, pa.z, pa.w,
                       pb.x, pb.y, pb.z, pb.w,
                       pc.x, pc.y, pc.z, pc.w};
        #pragma unroll
        for (int g = 0; g < NG; ++g)
            z[g] += h0 * u[0][g] + h1 * u[1][g] + h2 * u[2][g];

        // gate order: i = z[0:3], f = z[3:6], g = z[6:9], o = z[9:12]
        float ig0 = fsig(z[0]),  ig1 = fsig(z[1]),  ig2 = fsig(z[2]);
        float fg0 = fsig(z[3]),  fg1 = fsig(z[4]),  fg2 = fsig(z[5]);
        float gg0 = ftanh(z[6]), gg1 = ftanh(z[7]), gg2 = ftanh(z[8]);
        float og0 = fsig(z[9]),  og1 = fsig(z[10]), og2 = fsig(z[11]);

        c0 = fg0 * c0 + ig0 * gg0;
        c1 = fg1 * c1 + ig1 * gg1;
        c2 = fg2 * c2 + ig2 * gg2;

        h0 = og0 * ftanh(c0);
        h1 = og1 * ftanh(c1);
        h2 = og2 * ftanh(c2);

        pa = na; pb = nb_; pc = nc;
    }

    hs[b * 3 + 0] = h0; hs[b * 3 + 1] = h1; hs[b * 3 + 2] = h2;
    cs[b * 3 + 0] = c0; cs[b * 3 + 1] = c1; cs[b * 3 + 2] = c2;

    if (last) {
        float a = bd[0] + h0 * Wd[0] + h1 * Wd[1] + h2 * Wd[2];
        out[b] = fsig(a);
    }
}

extern "C" void kernel_launch(void* const* d_in, const int* in_sizes, int n_in,
                              void* d_out, int out_size, void* d_ws, size_t ws_size,
                              hipStream_t stream) {
    const float* x  = (const float*)d_in[0];
    const float* W  = (const float*)d_in[1];
    const float* U  = (const float*)d_in[2];
    const float* bv = (const float*)d_in[3];
    const float* Wd = (const float*)d_in[4];
    const float* bd = (const float*)d_in[5];
    float* out = (float*)d_out;

    float* state = (float*)d_ws;                         // h[NB*3], c[NB*3]
    size_t stateBytes = (size_t)NB * NH * 2 * sizeof(float);  // 98304, 16B-aligned
    float* pre = (float*)((char*)d_ws + stateBytes);

    // Largest power-of-two chunk of T that fits in workspace.
    int CT = NT;
    while (CT > 1 &&
           stateBytes + (size_t)NB * CT * NG * sizeof(float) > ws_size)
        CT >>= 1;
    int ctShift = 31 - __builtin_clz((unsigned)CT);
    int nCh = NT / CT;

    for (int ch = 0; ch < nCh; ++ch) {
        int t0 = ch * CT;
        dim3 g1((NB * CT) / 256);
        k1_proj<<<g1, 256, 0, stream>>>(x, W, bv, pre, t0, CT, ctShift);
        k2_scan<<<NB / 64, 64, 0, stream>>>(pre, U, Wd, bd, state, out,
                                            t0, CT, (ch == nCh - 1) ? 1 : 0);
    }
}